// Round 7
// baseline (643.729 us; speedup 1.0000x reference)
//
#include <hip/hip_runtime.h>

// Viterbi CRF decode: potentials [B,T,C] f32, transitions [C,C] f32 -> one-hot [B,T,C] f32
// B=256, T=1024, C=128.
//
// crf_fwd : max-only DP. Stashes q_t = max_p(alpha_{t-1}[p]+T[p][c]) (PRE-pot max)
//           into d_out as scratch (row 0 = zeros); LDS double-buffer carries
//           alpha_t = q_t + pot_t.
//           r7 KEY fix: 4-step loop body (not 8-step unroll). r2-r6 all showed
//           ~137 VALU inst/thread/step and VGPR_Count 40-48: the big unrolled
//           body's temp pressure made the allocator spill the loop-invariant
//           transitions to scratch, reloading them every step. Small body +
//           pk-math (v_pk_add/max_f32) + ds_read_b64 pairs + select-free DPP
//           row reduce (xor1,xor2,ror4,ror8) keeps the step lean.
// crf_bwd : per step t: M = q_t[tag] (exact, via readlane) -> backpointer =
//           first p with (q_{t-1}[p]+pot_{t-1}[p]) + T[p][tag] == M (bit-exact
//           replay of fwd's adds) -> ballot+ffs. No max-reduce in the chain.

typedef float f32x2 __attribute__((ext_vector_type(2)));

constexpr int NB = 256;
constexpr int NT = 1024;
constexpr int NC = 128;

template <int CTRL>
__device__ __forceinline__ float fmax_dpp(float v) {
  int x = __builtin_amdgcn_update_dpp(__float_as_int(v), __float_as_int(v),
                                      CTRL, 0xF, 0xF, false);
  return fmaxf(v, __int_as_float(x));
}
__device__ __forceinline__ f32x2 pkmax(f32x2 a, f32x2 b) {
  return __builtin_elementwise_max(a, b);
}
__device__ __forceinline__ float wave_max_to_lane63(float m) {
  m = fmax_dpp<0x111>(m);  // row_shr:1
  m = fmax_dpp<0x112>(m);  // row_shr:2
  m = fmax_dpp<0x114>(m);  // row_shr:4
  m = fmax_dpp<0x118>(m);  // row_shr:8
  m = fmax_dpp<0x142>(m);  // row_bcast:15
  m = fmax_dpp<0x143>(m);  // row_bcast:31 -> lane63 has full max
  return m;
}

// ---------------- forward ----------------
// alpha LDS layout: p at float index 12*(p>>3) + (p&7); chunk i = floats 12i..12i+7.

constexpr int ABUF = 192;

#define MKT(T, EA, EB)                                        \
  f32x2 T;                                                    \
  {                                                           \
    float _x = (EA), _y = (EB);                               \
    asm volatile("" : "+v"(_x), "+v"(_y));                    \
    T = f32x2{_x, _y};                                        \
  }

// One DP step. J,CUR compile-time; qsb/psb are uniform (scalar-base) pointers.
// PF: whether to prefetch pot row t+4 into PCJ.
#define STEP(PCJ, CUR, J, PF)                                               \
  do {                                                                      \
    const f32x2* _af = (CUR) ? afB : afA;                                   \
    f32x2 _a0 = _af[0], _a1 = _af[1], _a2 = _af[2], _a3 = _af[3];           \
    f32x2 _s0 = _a0 + T00, _s1 = _a1 + T10, _s2 = _a2 + T20,                \
          _s3 = _a3 + T30;                                                  \
    f32x2 _t = pkmax(pkmax(_s0, _s1), pkmax(_s2, _s3));                     \
    float _mj0 = fmaxf(_t.x, _t.y);                                         \
    _s0 = _a0 + T01; _s1 = _a1 + T11; _s2 = _a2 + T21; _s3 = _a3 + T31;     \
    _t = pkmax(pkmax(_s0, _s1), pkmax(_s2, _s3));                           \
    float _mj1 = fmaxf(_t.x, _t.y);                                         \
    _s0 = _a0 + T02; _s1 = _a1 + T12; _s2 = _a2 + T22; _s3 = _a3 + T32;     \
    _t = pkmax(pkmax(_s0, _s1), pkmax(_s2, _s3));                           \
    float _mj2 = fmaxf(_t.x, _t.y);                                         \
    _s0 = _a0 + T03; _s1 = _a1 + T13; _s2 = _a2 + T23; _s3 = _a3 + T33;     \
    _t = pkmax(pkmax(_s0, _s1), pkmax(_s2, _s3));                           \
    float _mj3 = fmaxf(_t.x, _t.y);                                         \
    /* select-free row reduce: after xor1,xor2,ror4,ror8 every lane of the  \
       16-lane row holds the full 16-chunk max (max is exactly assoc.) */   \
    _mj0 = fmax_dpp<0xB1>(_mj0);  _mj1 = fmax_dpp<0xB1>(_mj1);              \
    _mj2 = fmax_dpp<0xB1>(_mj2);  _mj3 = fmax_dpp<0xB1>(_mj3);              \
    _mj0 = fmax_dpp<0x4E>(_mj0);  _mj1 = fmax_dpp<0x4E>(_mj1);              \
    _mj2 = fmax_dpp<0x4E>(_mj2);  _mj3 = fmax_dpp<0x4E>(_mj3);              \
    _mj0 = fmax_dpp<0x124>(_mj0); _mj1 = fmax_dpp<0x124>(_mj1);             \
    _mj2 = fmax_dpp<0x124>(_mj2); _mj3 = fmax_dpp<0x124>(_mj3);             \
    _mj0 = fmax_dpp<0x128>(_mj0); _mj1 = fmax_dpp<0x128>(_mj1);             \
    _mj2 = fmax_dpp<0x128>(_mj2); _mj3 = fmax_dpp<0x128>(_mj3);             \
    if (wr) {                                                               \
      float _s01 = (i & 1) ? _mj1 : _mj0;                                   \
      float _s23 = (i & 1) ? _mj3 : _mj2;                                   \
      float _q = (i & 2) ? _s23 : _s01;                                     \
      alpha[((CUR) ^ 1) * ABUF + widx] = _q + (PCJ);                        \
      qsb[(J) * NC + cw] = _q;                                              \
      if (PF) (PCJ) = psb[(J) * NC + cw];                                   \
    }                                                                       \
    asm volatile("s_waitcnt lgkmcnt(0)\n\ts_barrier" ::: "memory");         \
  } while (0)

__global__ __launch_bounds__(512, 2)
void crf_fwd(const float* __restrict__ pot, const float* __restrict__ trans,
             float* __restrict__ out) {
  __shared__ __align__(16) float alpha[2 * ABUF];

  const int tid = threadIdx.x;
  const int b = blockIdx.x;
  const int w = tid >> 6;          // wave 0..7
  const int l = tid & 63;          // lane
  const int r = l >> 4;            // row 0..3
  const int i = l & 15;            // p-chunk (position in the 16-lane DPP row)
  const int g = w * 4 + r;         // c-quad 0..31
  const bool wr = (i >= 12);       // writer lanes: one per c in the quad
  const int cw = 4 * g + (i & 3);  // writer's c (i=12->c0 .. i=15->c3)
  const int widx = 12 * (cw >> 3) + (cw & 7);

  const float* potb = pot + (size_t)b * NT * NC;
  float* outb = out + (size_t)b * NT * NC;

  // transitions into 16 named f32x2 regs: Tkj = (T[8i+2k][4g+j], T[8i+2k+1][4g+j])
  const float* tb = trans + (8 * i) * NC + 4 * g;
  float4 L0 = *(const float4*)(tb + 0 * NC);
  float4 L1 = *(const float4*)(tb + 1 * NC);
  float4 L2 = *(const float4*)(tb + 2 * NC);
  float4 L3 = *(const float4*)(tb + 3 * NC);
  float4 L4 = *(const float4*)(tb + 4 * NC);
  float4 L5 = *(const float4*)(tb + 5 * NC);
  float4 L6 = *(const float4*)(tb + 6 * NC);
  float4 L7 = *(const float4*)(tb + 7 * NC);
  MKT(T00, L0.x, L1.x) MKT(T01, L0.y, L1.y) MKT(T02, L0.z, L1.z) MKT(T03, L0.w, L1.w)
  MKT(T10, L2.x, L3.x) MKT(T11, L2.y, L3.y) MKT(T12, L2.z, L3.z) MKT(T13, L2.w, L3.w)
  MKT(T20, L4.x, L5.x) MKT(T21, L4.y, L5.y) MKT(T22, L4.z, L5.z) MKT(T23, L4.w, L5.w)
  MKT(T30, L6.x, L7.x) MKT(T31, L6.y, L7.y) MKT(T32, L6.z, L7.z) MKT(T33, L6.w, L7.w)

  float pc0, pc1, pc2, pc3;  // pot prefetch, depth 4 (writer lanes only)
  if (wr) {
    alpha[widx] = potb[cw];   // alpha_0 = pot[:,0,:]
    outb[cw] = 0.0f;          // q_0 := 0
    pc0 = potb[1 * NC + cw]; pc1 = potb[2 * NC + cw];
    pc2 = potb[3 * NC + cw]; pc3 = potb[4 * NC + cw];
  }
  asm volatile("s_waitcnt lgkmcnt(0)\n\ts_barrier" ::: "memory");

  const f32x2* afA = (const f32x2*)(alpha) + 6 * i;          // chunk i pairs
  const f32x2* afB = (const f32x2*)(alpha + ABUF) + 6 * i;

  float* qsb = outb + 1 * NC;          // q-store base: row t0 of the group
  const float* psb = potb + 5 * NC;    // prefetch base: row t0+4

  // 254 groups of 4: t = 1..1016 (CUR alternates 0,1 from t=1)
  for (int grp = 0; grp < 254; ++grp) {
    STEP(pc0, 0, 0, 1); STEP(pc1, 1, 1, 1);
    STEP(pc2, 0, 2, 1); STEP(pc3, 1, 3, 1);
    qsb += 4 * NC; psb += 4 * NC;
  }
  // group 254: t = 1017..1020, prefetch only rows 1021..1023 (J=3 would be OOB)
  STEP(pc0, 0, 0, 1); STEP(pc1, 1, 1, 1);
  STEP(pc2, 0, 2, 1); STEP(pc3, 1, 3, 0);
  qsb += 4 * NC;
  // tail: t = 1021..1023
  STEP(pc0, 0, 0, 0); STEP(pc1, 1, 1, 0); STEP(pc2, 0, 2, 0);
}

// ---------------- backward ----------------
// tTp[c][l] = (T[l][c], T[64+l][c]) as float2 in LDS (64 KiB).
// Wave 0 chases; per step only an equality scan against M = q_t[tag].

__global__ __launch_bounds__(256)
void crf_bwd(const float* __restrict__ pot, const float* __restrict__ trans,
             float* __restrict__ out) {
  extern __shared__ float tTf[];   // float2[NC][64] interleaved
  const int tid = threadIdx.x;
  const int b = blockIdx.x;
  const float* potb = pot + (size_t)b * NT * NC;
  float* outb = out + (size_t)b * NT * NC;

  {
    const int rr = tid >> 1;   // source row p of trans
    const int h = tid & 1;     // which half of the row
    const float4* src = (const float4*)(trans + rr * NC + h * 64);
    const int lo = rr & 63, hb = rr >> 6;
    #pragma unroll
    for (int j = 0; j < 16; ++j) {
      float4 q = src[j];
      int cb = h * 64 + 4 * j;
      tTf[(cb + 0) * 128 + lo * 2 + hb] = q.x;
      tTf[(cb + 1) * 128 + lo * 2 + hb] = q.y;
      tTf[(cb + 2) * 128 + lo * 2 + hb] = q.z;
      tTf[(cb + 3) * 128 + lo * 2 + hb] = q.w;
    }
  }
  __syncthreads();
  if (tid >= 64) return;
  const int l = tid;
  const f32x2* tTp = (const f32x2*)tTf;

  // init at t = NT-1: alpha_last = q_last + pot_last; full argmax once
  float qlo_t = outb[(NT - 1) * NC + l];
  float qhi_t = outb[(NT - 1) * NC + 64 + l];
  float alo_t = qlo_t + potb[(NT - 1) * NC + l];
  float ahi_t = qhi_t + potb[(NT - 1) * NC + 64 + l];
  float m0 = wave_max_to_lane63(fmaxf(alo_t, ahi_t));
  float M0 = __int_as_float(__builtin_amdgcn_readlane(__float_as_int(m0), 63));
  unsigned long long bl = __ballot(alo_t == M0);
  unsigned long long bh = __ballot(ahi_t == M0);
  int tag = bl ? (__ffsll((long long)bl) - 1)
               : (64 + __ffsll((long long)bh) - 1);

  // prefetch rows 1022..1015 (q and pot), precompute alpha
  float cqlo[8], cqhi[8], calo[8], cahi[8];
  float nqlo[8], nqhi[8], nplo[8], nphi[8];
  #pragma unroll
  for (int j = 0; j < 8; ++j) {
    int rw = NT - 2 - j;
    cqlo[j] = outb[rw * NC + l];
    cqhi[j] = outb[rw * NC + 64 + l];
    calo[j] = cqlo[j] + potb[rw * NC + l];
    cahi[j] = cqhi[j] + potb[rw * NC + 64 + l];
  }

  for (int g = 0; g < 128; ++g) {
    #pragma unroll
    for (int j = 0; j < 8; ++j) {      // prefetch group g+1
      int rw = NT - 10 - 8 * g - j;
      if (rw < 0) rw = 0;
      nqlo[j] = outb[rw * NC + l];
      nqhi[j] = outb[rw * NC + 64 + l];
      nplo[j] = potb[rw * NC + l];
      nphi[j] = potb[rw * NC + 64 + l];
    }
    #pragma unroll
    for (int j = 0; j < 8; ++j) {
      int t = NT - 1 - 8 * g - j;
      if (t >= 1) {
        outb[t * NC + l]      = (l == tag) ? 1.0f : 0.0f;
        outb[t * NC + 64 + l] = (64 + l == tag) ? 1.0f : 0.0f;
        int Mlo = __builtin_amdgcn_readlane(__float_as_int(qlo_t), tag & 63);
        int Mhi = __builtin_amdgcn_readlane(__float_as_int(qhi_t), tag & 63);
        float M = __int_as_float((tag < 64) ? Mlo : Mhi);
        f32x2 tt = tTp[tag * 64 + l];
        float vlo = calo[j] + tt.x;
        float vhi = cahi[j] + tt.y;
        unsigned long long el = __ballot(vlo == M);
        unsigned long long eh = __ballot(vhi == M);
        tag = el ? (__ffsll((long long)el) - 1)
                 : (64 + __ffsll((long long)eh) - 1);
        qlo_t = cqlo[j];
        qhi_t = cqhi[j];
      }
    }
    #pragma unroll
    for (int j = 0; j < 8; ++j) {
      cqlo[j] = nqlo[j]; cqhi[j] = nqhi[j];
      calo[j] = nqlo[j] + nplo[j];
      cahi[j] = nqhi[j] + nphi[j];
    }
  }
  outb[l]      = (l == tag) ? 1.0f : 0.0f;
  outb[64 + l] = (64 + l == tag) ? 1.0f : 0.0f;
}

// ---------------- launch ----------------

extern "C" void kernel_launch(void* const* d_in, const int* in_sizes, int n_in,
                              void* d_out, int out_size, void* d_ws, size_t ws_size,
                              hipStream_t stream) {
  const float* pot   = (const float*)d_in[0];
  const float* trans = (const float*)d_in[1];
  float* out = (float*)d_out;

  hipFuncSetAttribute((const void*)crf_bwd,
                      hipFuncAttributeMaxDynamicSharedMemorySize, NC * NC * 4);

  crf_fwd<<<NB, 512, 0, stream>>>(pot, trans, out);
  crf_bwd<<<NB, 256, NC * NC * 4, stream>>>(pot, trans, out);
}